// Round 5
// baseline (441.732 us; speedup 1.0000x reference)
//
#include <hip/hip_runtime.h>
#include <stdint.h>

#define S_TOK 8192
#define MDIM  1024
#define HDIM  4096
#define ODIM  1024
#define NEXP  4
#define CAP   2048   // ceil(S/E)

typedef __attribute__((ext_vector_type(8))) short short8;
typedef __attribute__((ext_vector_type(4))) float floatx4;

__device__ __forceinline__ unsigned short f2bf(float x) {
  union { float f; unsigned u; } v; v.f = x;
  unsigned r = v.u + 0x7FFFu + ((v.u >> 16) & 1u);   // RNE
  return (unsigned short)(r >> 16);
}

__device__ __forceinline__ void gl_lds16(const void* g, void* l) {
  __builtin_amdgcn_global_load_lds(
      (const __attribute__((address_space(1))) void*)g,
      (__attribute__((address_space(3))) void*)l, 16, 0, 0);
}

// gelu(x) = 0.5x(1+tanh(z)) = x * sigmoid(2z), z = 0.79788456(x + 0.044715 x^3)
__device__ __forceinline__ float gelu_tanh(float x) {
  float p = x * x;
  float t = x * (1.5957691216f + 0.0713548353f * p);   // 2z
  float E = __expf(-t);
  return __fdividef(x, 1.0f + E);
}

// Swizzled staging source: LDS slot s (of 4 per 64B row) receives row element
// c16 = s ^ ((row>>1)&3).  Reads use the same XOR -> 8-way bank conflict
// becomes 2-way (free).  LDS itself stays linear (global_load_lds constraint).
__device__ __forceinline__ const char* stage_src(const char* base, int linoff,
                                                 int rowstride) {
  int row  = linoff >> 6;
  int slot = (linoff >> 4) & 3;
  int c16  = slot ^ ((row >> 1) & 3);
  return base + (size_t)row * rowstride + (c16 << 4);
}

// ---------------- gate: logits (fp64 acc), softmax, argmax, gate sums ----------
__global__ __launch_bounds__(256) void gate_kernel(
    const float* __restrict__ feat, const float* __restrict__ gw,
    int* __restrict__ idx, float* __restrict__ gval, float* __restrict__ gsum)
{
  int wave = threadIdx.x >> 6, lane = threadIdx.x & 63;
  int s = blockIdx.x * 4 + wave;
  const float4* f4 = (const float4*)(feat + (size_t)s * MDIM);
  double a0 = 0, a1 = 0, a2 = 0, a3 = 0;
  #pragma unroll
  for (int j = 0; j < 4; ++j) {
    int m4 = lane + j * 64;
    float4 x = f4[m4];
    #pragma unroll
    for (int c = 0; c < 4; ++c) {
      float xv = (c == 0) ? x.x : (c == 1) ? x.y : (c == 2) ? x.z : x.w;
      float4 w = ((const float4*)gw)[m4 * 4 + c];
      a0 += (double)xv * w.x; a1 += (double)xv * w.y;
      a2 += (double)xv * w.z; a3 += (double)xv * w.w;
    }
  }
  #pragma unroll
  for (int off = 32; off; off >>= 1) {
    a0 += __shfl_down(a0, off); a1 += __shfl_down(a1, off);
    a2 += __shfl_down(a2, off); a3 += __shfl_down(a3, off);
  }
  __shared__ float bs[4];
  if (threadIdx.x < 4) bs[threadIdx.x] = 0.f;
  __syncthreads();
  if (lane == 0) {
    double lg[4] = {a0, a1, a2, a3};
    double mx = lg[0]; int bi = 0;
    #pragma unroll
    for (int e = 1; e < 4; ++e) if (lg[e] > mx) { mx = lg[e]; bi = e; }  // first-max
    float ex[4]; float den = 0.f;
    #pragma unroll
    for (int e = 0; e < 4; ++e) { ex[e] = __expf((float)(lg[e] - mx)); den += ex[e]; }
    float inv = 1.f / den;
    idx[s]  = bi;
    gval[s] = ex[bi] * inv;
    #pragma unroll
    for (int e = 0; e < 4; ++e) atomicAdd(&bs[e], ex[e] * inv);
  }
  __syncthreads();
  if (threadIdx.x < 4) atomicAdd(&gsum[threadIdx.x], bs[threadIdx.x]);
}

// -------- ordered per-expert rank scan: 16 waves, LDS wave-prefix, l_aux -------
__global__ __launch_bounds__(1024) void scan_kernel(
    const int* __restrict__ idx, int* __restrict__ perm,
    int* __restrict__ ne, const float* __restrict__ gsum,
    float* __restrict__ laux)
{
  const int tid = threadIdx.x, wave = tid >> 6, lane = tid & 63;
  __shared__ int cnt[16][4];
  __shared__ int off[16][4];
  __shared__ int tot[4];
  unsigned long long below = (lane == 0) ? 0ull : ((~0ull) >> (64 - lane));

  int myE[8], loc[8];
  int c[4] = {0, 0, 0, 0};
  #pragma unroll
  for (int j = 0; j < 8; ++j) {
    int s = wave * 512 + j * 64 + lane;
    int ev = idx[s];
    myE[j] = ev;
    #pragma unroll
    for (int e = 0; e < 4; ++e) {
      unsigned long long mb = __ballot(ev == e);
      if (ev == e) loc[j] = c[e] + __popcll(mb & below);
      c[e] += __popcll(mb);   // wave-uniform
    }
  }
  if (lane == 0) {
    #pragma unroll
    for (int e = 0; e < 4; ++e) cnt[wave][e] = c[e];
  }
  __syncthreads();
  if (tid < 64) {            // 16 waves x 4 experts
    int w = tid >> 2, e = tid & 3;
    int o = 0;
    for (int w2 = 0; w2 < 16; ++w2) if (w2 < w) o += cnt[w2][e];
    off[w][e] = o;
    if (w == 15) tot[e] = o + cnt[15][e];
  }
  __syncthreads();
  #pragma unroll
  for (int j = 0; j < 8; ++j) {
    int s = wave * 512 + j * 64 + lane;
    int e = myE[j];
    int rank = off[wave][e] + loc[j];
    if (rank < CAP) perm[e * CAP + rank] = s;   // dropped tokens: no slot
  }
  if (tid < 4) ne[tid] = tot[tid] < CAP ? tot[tid] : CAP;
  if (tid == 0) {   // l_aux: PRE-capacity counts x full softmax means
    float l = 0.f;
    #pragma unroll
    for (int e = 0; e < 4; ++e)
      l += (gsum[e] * (1.0f / S_TOK)) * ((float)tot[e] * (1.0f / S_TOK));
    *laux = l * (float)NEXP;
  }
}

// ---------------- cast + transpose weights: [R,C] f32 -> [C,R] bf16 ------------
__global__ __launch_bounds__(256) void transpose_cast(
    const float* __restrict__ in, unsigned short* __restrict__ out, int R, int Cc)
{
  __shared__ unsigned short tile[64][66];
  in  += (size_t)blockIdx.z * R * Cc;
  out += (size_t)blockIdx.z * R * Cc;
  int c0 = blockIdx.x * 64, r0 = blockIdx.y * 64;
  int tx = threadIdx.x & 15;
  int ty = threadIdx.x >> 4;
  #pragma unroll
  for (int p = 0; p < 4; ++p) {
    int r = ty + p * 16;
    float4 v = *(const float4*)(in + (size_t)(r0 + r) * Cc + c0 + tx * 4);
    tile[r][tx * 4 + 0] = f2bf(v.x);
    tile[r][tx * 4 + 1] = f2bf(v.y);
    tile[r][tx * 4 + 2] = f2bf(v.z);
    tile[r][tx * 4 + 3] = f2bf(v.w);
  }
  __syncthreads();
  #pragma unroll
  for (int p = 0; p < 4; ++p) {
    int c = ty + p * 16;
    ushort4 o;
    o.x = tile[tx * 4 + 0][c];
    o.y = tile[tx * 4 + 1][c];
    o.z = tile[tx * 4 + 2][c];
    o.w = tile[tx * 4 + 3][c];
    *(ushort4*)(out + (size_t)(c0 + c) * R + r0 + tx * 4) = o;
  }
}

// ---------------- gather kept tokens -> bf16 dispatch buffer -------------------
__global__ __launch_bounds__(256) void gather_kernel(
    const float* __restrict__ feat, const int* __restrict__ perm,
    const int* __restrict__ ne, unsigned short* __restrict__ disp)
{
  int b = blockIdx.x;
  int e = b >> 11, c = b & (CAP - 1);
  int m = threadIdx.x * 4;
  ushort4 o;
  if (c < ne[e]) {
    int s = perm[b];
    float4 v = *(const float4*)(feat + (size_t)s * MDIM + m);
    o.x = f2bf(v.x); o.y = f2bf(v.y); o.z = f2bf(v.z); o.w = f2bf(v.w);
  } else {
    o.x = o.y = o.z = o.w = 0;   // empty slot -> zero row (h row = gelu(0)=0)
  }
  *(ushort4*)(disp + (size_t)b * MDIM + m) = o;
}

// ---------------- fc1: disp[E*C,1024] @ w1t[E,4096,1024] -> gelu -> h bf16 -----
// R5: L2-tiled XCD-chunked 1D grid. xcd = b&7 (HW round-robin). Per XCD:
// 256 wgs, e = xcd>>1, mb-half = xcd&1; order (nbg, mb, nbl) so the inner
// runs share a B-panel (256KB) and the 8 A-panels (2MB) stay L2-resident
// across nbg -> staging hits L2, not L3 (R4 theory: GEMMs are L3-BW-bound).
__global__ __launch_bounds__(256) void fc1_kernel(
    const unsigned short* __restrict__ A, const unsigned short* __restrict__ Bt,
    const float* __restrict__ b1, unsigned short* __restrict__ Hb)
{
  const int b = blockIdx.x;                 // 0..2047
  const int xcd = b & 7, r = b >> 3;        // r: 0..255
  const int e = xcd >> 1;
  const int nbg = r >> 5, mbo = (r >> 2) & 7, nbl = r & 3;
  const int nb = nbg * 4 + nbl;             // 0..31
  const int mb = (xcd & 1) * 8 + mbo;       // 0..15
  const int tid = threadIdx.x, wave = tid >> 6, lane = tid & 63;

  __shared__ __align__(16) unsigned short smA[3 * 128 * 32];  // 3 x 8 KB
  __shared__ __align__(16) unsigned short smB[3 * 128 * 32];  // 3 x 8 KB

  const char* Ag = (const char*)(A + ((size_t)e * CAP + (size_t)mb * 128) * MDIM);
  const char* Bg = (const char*)(Bt + ((size_t)e * HDIM + (size_t)nb * 128) * MDIM);

  const int boff0 = (wave * 2 + 0) * 1024 + lane * 16;   // linear byte in 8KB tile
  const int boff1 = (wave * 2 + 1) * 1024 + lane * 16;
  const char* agp0 = stage_src(Ag, boff0, 2048);
  const char* agp1 = stage_src(Ag, boff1, 2048);
  const char* bgp0 = stage_src(Bg, boff0, 2048);
  const char* bgp1 = stage_src(Bg, boff1, 2048);
  const int ldsw0 = (wave * 2 + 0) * 512;   // shorts
  const int ldsw1 = (wave * 2 + 1) * 512;

  const int wm = (wave & 1) * 64, wn = (wave >> 1) * 64;
  const int fr = lane & 15, fq = lane >> 4;
  const int sqA = ((fq ^ ((wm + fr) >> 1)) & 3) * 8;   // swizzled 16B slot (shorts)
  const int sqB = ((fq ^ ((wn + fr) >> 1)) & 3) * 8;

  floatx4 acc[4][4] = {};

  const int NT = MDIM / 32;                 // 32 K-tiles
  int c0 = 0, c1 = 1, c2 = 2;

  gl_lds16(agp0 + 0,  smA + 0 * 4096 + ldsw0);
  gl_lds16(agp1 + 0,  smA + 0 * 4096 + ldsw1);
  gl_lds16(bgp0 + 0,  smB + 0 * 4096 + ldsw0);
  gl_lds16(bgp1 + 0,  smB + 0 * 4096 + ldsw1);
  gl_lds16(agp0 + 64, smA + 1 * 4096 + ldsw0);
  gl_lds16(agp1 + 64, smA + 1 * 4096 + ldsw1);
  gl_lds16(bgp0 + 64, smB + 1 * 4096 + ldsw0);
  gl_lds16(bgp1 + 64, smB + 1 * 4096 + ldsw1);
  asm volatile("s_waitcnt vmcnt(4)" ::: "memory");
  __builtin_amdgcn_s_barrier();

  for (int kt = 0; kt < NT; ++kt) {
    if (kt + 2 < NT) {
      int kb = (kt + 2) * 64;
      gl_lds16(agp0 + kb, smA + c2 * 4096 + ldsw0);
      gl_lds16(agp1 + kb, smA + c2 * 4096 + ldsw1);
      gl_lds16(bgp0 + kb, smB + c2 * 4096 + ldsw0);
      gl_lds16(bgp1 + kb, smB + c2 * 4096 + ldsw1);
    }
    const unsigned short* sA = smA + c0 * 4096;
    const unsigned short* sB = smB + c0 * 4096;
    short8 af[4], bfr[4];
    #pragma unroll
    for (int i = 0; i < 4; ++i)
      af[i] = *(const short8*)&sA[(wm + i * 16 + fr) * 32 + sqA];
    #pragma unroll
    for (int j = 0; j < 4; ++j)
      bfr[j] = *(const short8*)&sB[(wn + j * 16 + fr) * 32 + sqB];
    #pragma unroll
    for (int i = 0; i < 4; ++i)
      #pragma unroll
      for (int j = 0; j < 4; ++j)   // swapped operands: acc = D^T
        acc[i][j] = __builtin_amdgcn_mfma_f32_16x16x32_bf16(bfr[j], af[i], acc[i][j], 0, 0, 0);
    if (kt + 1 < NT) {
      if (kt + 2 < NT) asm volatile("s_waitcnt vmcnt(4)" ::: "memory");
      else             asm volatile("s_waitcnt vmcnt(0)" ::: "memory");
      __builtin_amdgcn_s_barrier();
    }
    int t = c0; c0 = c1; c1 = c2; c2 = t;
  }

  // D^T layout: value(i,j,r) at m = wm+i*16+fr, n = wn+j*16+fq*4+r
  unsigned short* Hrow = Hb + (size_t)e * CAP * HDIM;
  #pragma unroll
  for (int j = 0; j < 4; ++j) {
    int gn0 = nb * 128 + wn + j * 16 + fq * 4;
    float4 bv = *(const float4*)&b1[e * HDIM + gn0];
    #pragma unroll
    for (int i = 0; i < 4; ++i) {
      int m = mb * 128 + wm + i * 16 + fr;
      ushort4 o;
      o.x = f2bf(gelu_tanh(acc[i][j][0] + bv.x));
      o.y = f2bf(gelu_tanh(acc[i][j][1] + bv.y));
      o.z = f2bf(gelu_tanh(acc[i][j][2] + bv.z));
      o.w = f2bf(gelu_tanh(acc[i][j][3] + bv.w));
      *(ushort4*)&Hrow[(size_t)m * HDIM + gn0] = o;
    }
  }
}

// ---------------- fc2: h[E*C,4096] @ w2t[E,1024,4096] -> gated scatter ---------
// R5: BM=128 (fc1 geometry -> staged bytes 1.57 -> 1.02 GB, 2x MFMA density;
// R1's BM=128 failure lacked pipeline+swizzle and used atomics).  512 blocks,
// L2-tiled XCD-chunk: per XCD 64 wgs, order (mbg, nb, mbl) so 4 A-panels
// (4MB) stay L2-resident while B streams.
__global__ __launch_bounds__(256) void fc2_kernel(
    const unsigned short* __restrict__ A, const unsigned short* __restrict__ Bt,
    const float* __restrict__ b2, const int* __restrict__ perm,
    const int* __restrict__ ne, const float* __restrict__ gval,
    float* __restrict__ out)
{
  const int b = blockIdx.x;                 // 0..511
  const int xcd = b & 7, r = b >> 3;        // r: 0..63
  const int e = xcd >> 1;
  const int mbg = r >> 5, nb = (r >> 2) & 7, mbl = r & 3;
  const int mb = (xcd & 1) * 8 + mbg * 4 + mbl;   // 0..15
  const int tid = threadIdx.x, wave = tid >> 6, lane = tid & 63;

  __shared__ __align__(16) unsigned short smA[3 * 128 * 32];   // 3 x 8 KB
  __shared__ __align__(16) unsigned short smB[3 * 128 * 32];   // 3 x 8 KB

  const char* Ag = (const char*)(A + ((size_t)e * CAP + (size_t)mb * 128) * HDIM);
  const char* Bg = (const char*)(Bt + ((size_t)e * ODIM + (size_t)nb * 128) * HDIM);

  const int boff0 = (wave * 2 + 0) * 1024 + lane * 16;
  const int boff1 = (wave * 2 + 1) * 1024 + lane * 16;
  const char* agp0 = stage_src(Ag, boff0, 8192);
  const char* agp1 = stage_src(Ag, boff1, 8192);
  const char* bgp0 = stage_src(Bg, boff0, 8192);
  const char* bgp1 = stage_src(Bg, boff1, 8192);
  const int ldsw0 = (wave * 2 + 0) * 512;
  const int ldsw1 = (wave * 2 + 1) * 512;

  const int wm = (wave & 1) * 64, wn = (wave >> 1) * 64;
  const int fr = lane & 15, fq = lane >> 4;
  const int sqA = ((fq ^ ((wm + fr) >> 1)) & 3) * 8;
  const int sqB = ((fq ^ ((wn + fr) >> 1)) & 3) * 8;

  floatx4 acc[4][4] = {};

  const int NT = HDIM / 32;                 // 128 K-tiles
  int c0 = 0, c1 = 1, c2 = 2;

  gl_lds16(agp0 + 0,  smA + 0 * 4096 + ldsw0);
  gl_lds16(agp1 + 0,  smA + 0 * 4096 + ldsw1);
  gl_lds16(bgp0 + 0,  smB + 0 * 4096 + ldsw0);
  gl_lds16(bgp1 + 0,  smB + 0 * 4096 + ldsw1);
  gl_lds16(agp0 + 64, smA + 1 * 4096 + ldsw0);
  gl_lds16(agp1 + 64, smA + 1 * 4096 + ldsw1);
  gl_lds16(bgp0 + 64, smB + 1 * 4096 + ldsw0);
  gl_lds16(bgp1 + 64, smB + 1 * 4096 + ldsw1);
  asm volatile("s_waitcnt vmcnt(4)" ::: "memory");
  __builtin_amdgcn_s_barrier();

  for (int kt = 0; kt < NT; ++kt) {
    if (kt + 2 < NT) {
      int kb = (kt + 2) * 64;
      gl_lds16(agp0 + kb, smA + c2 * 4096 + ldsw0);
      gl_lds16(agp1 + kb, smA + c2 * 4096 + ldsw1);
      gl_lds16(bgp0 + kb, smB + c2 * 4096 + ldsw0);
      gl_lds16(bgp1 + kb, smB + c2 * 4096 + ldsw1);
    }
    const unsigned short* sA = smA + c0 * 4096;
    const unsigned short* sB = smB + c0 * 4096;
    short8 af[4], bfr[4];
    #pragma unroll
    for (int i = 0; i < 4; ++i)
      af[i] = *(const short8*)&sA[(wm + i * 16 + fr) * 32 + sqA];
    #pragma unroll
    for (int j = 0; j < 4; ++j)
      bfr[j] = *(const short8*)&sB[(wn + j * 16 + fr) * 32 + sqB];
    #pragma unroll
    for (int i = 0; i < 4; ++i)
      #pragma unroll
      for (int j = 0; j < 4; ++j)   // swapped operands: acc = D^T
        acc[i][j] = __builtin_amdgcn_mfma_f32_16x16x32_bf16(bfr[j], af[i], acc[i][j], 0, 0, 0);
    if (kt + 1 < NT) {
      if (kt + 2 < NT) asm volatile("s_waitcnt vmcnt(4)" ::: "memory");
      else             asm volatile("s_waitcnt vmcnt(0)" ::: "memory");
      __builtin_amdgcn_s_barrier();
    }
    int t = c0; c0 = c1; c1 = c2; c2 = t;
  }

  // D^T: value(i,j,r) at token-slot c = mb*128+wm+i*16+fr, n = wn+j*16+fq*4+r
  const int nE = ne[e];
  float4 b2v[4];
  #pragma unroll
  for (int j = 0; j < 4; ++j)
    b2v[j] = *(const float4*)&b2[e * ODIM + nb * 128 + wn + j * 16 + fq * 4];
  #pragma unroll
  for (int i = 0; i < 4; ++i) {
    int c = mb * 128 + wm + i * 16 + fr;
    if (c < nE) {
      int s = perm[e * CAP + c];
      float g = gval[s];
      float* orow = out + (size_t)s * ODIM + nb * 128 + wn + fq * 4;
      #pragma unroll
      for (int j = 0; j < 4; ++j) {
        float4 o;
        o.x = (acc[i][j][0] + b2v[j].x) * g;
        o.y = (acc[i][j][1] + b2v[j].y) * g;
        o.z = (acc[i][j][2] + b2v[j].z) * g;
        o.w = (acc[i][j][3] + b2v[j].w) * g;
        *(float4*)&orow[j * 16] = o;
      }
    }
  }
}

// ------------------------------- launch ---------------------------------------
extern "C" void kernel_launch(void* const* d_in, const int* in_sizes, int n_in,
                              void* d_out, int out_size, void* d_ws, size_t ws_size,
                              hipStream_t stream) {
  const float* feat = (const float*)d_in[0];
  const float* gw   = (const float*)d_in[1];
  const float* w1   = (const float*)d_in[2];
  const float* b1   = (const float*)d_in[3];
  const float* w2   = (const float*)d_in[4];
  const float* b2   = (const float*)d_in[5];
  float* out = (float*)d_out;

  char* ws = (char*)d_ws;
  unsigned short* wt   = (unsigned short*)(ws);                  // 33,554,432 B
  unsigned short* hbuf = (unsigned short*)(ws + 33554432);       // 67,108,864 B
  unsigned short* disp = (unsigned short*)(ws + 100663296);      // 16,777,216 B
  int*   idx  = (int*)  (ws + 117440512);
  float* gval = (float*)(ws + 117473280);
  int*   perm = (int*)  (ws + 117506048);
  float* gsum = (float*)(ws + 117538816);
  int*   ne   = (int*)  (ws + 117538832);

  hipMemsetAsync(d_out, 0, (size_t)S_TOK * ODIM * sizeof(float), stream);
  hipMemsetAsync(ws + 117538816, 0, 32, stream);

  gate_kernel<<<S_TOK / 4, 256, 0, stream>>>(feat, gw, idx, gval, gsum);
  scan_kernel<<<1, 1024, 0, stream>>>(idx, perm, ne, gsum, out + (size_t)S_TOK * ODIM);
  transpose_cast<<<dim3(HDIM / 64, MDIM / 64, NEXP), 256, 0, stream>>>(w1, wt, MDIM, HDIM);
  gather_kernel<<<NEXP * CAP, 256, 0, stream>>>(feat, perm, ne, disp);
  fc1_kernel<<<2048, 256, 0, stream>>>(disp, wt, b1, hbuf);
  transpose_cast<<<dim3(ODIM / 64, HDIM / 64, NEXP), 256, 0, stream>>>(w2, wt, HDIM, ODIM);
  fc2_kernel<<<512, 256, 0, stream>>>(hbuf, wt, b2, perm, ne, gval, out);
}

// Round 6
// 419.323 us; speedup vs baseline: 1.0534x; 1.0534x over previous
//
#include <hip/hip_runtime.h>
#include <stdint.h>

#define S_TOK 8192
#define MDIM  1024
#define HDIM  4096
#define ODIM  1024
#define NEXP  4
#define CAP   2048   // ceil(S/E)

typedef __attribute__((ext_vector_type(8))) short short8;
typedef __attribute__((ext_vector_type(4))) float floatx4;

__device__ __forceinline__ unsigned short f2bf(float x) {
  union { float f; unsigned u; } v; v.f = x;
  unsigned r = v.u + 0x7FFFu + ((v.u >> 16) & 1u);   // RNE
  return (unsigned short)(r >> 16);
}

__device__ __forceinline__ void gl_lds16(const void* g, void* l) {
  __builtin_amdgcn_global_load_lds(
      (const __attribute__((address_space(1))) void*)g,
      (__attribute__((address_space(3))) void*)l, 16, 0, 0);
}

// gelu(x) = 0.5x(1+tanh(z)) = x * sigmoid(2z), z = 0.79788456(x + 0.044715 x^3)
__device__ __forceinline__ float gelu_tanh(float x) {
  float p = x * x;
  float t = x * (1.5957691216f + 0.0713548353f * p);   // 2z
  float E = __expf(-t);
  return __fdividef(x, 1.0f + E);
}

// Swizzled staging source: LDS slot s (of 4 per 64B row) receives row element
// c16 = s ^ ((row>>1)&3).  Reads use the same XOR -> 8-way bank conflict
// becomes 2-way (free).  LDS itself stays linear (global_load_lds constraint).
__device__ __forceinline__ const char* stage_src(const char* base, int linoff,
                                                 int rowstride) {
  int row  = linoff >> 6;
  int slot = (linoff >> 4) & 3;
  int c16  = slot ^ ((row >> 1) & 3);
  return base + (size_t)row * rowstride + (c16 << 4);
}

// ---------------- prep: gate + w1 transpose + d_out zero, one launch ----------
// All three are mutually independent; fusing removes 2 dispatches and
// overlaps the BW-bound transpose/zero with the compute-bound gate.
__global__ __launch_bounds__(256) void prep_kernel(
    const float* __restrict__ feat, const float* __restrict__ gw,
    const float* __restrict__ w1,
    int* __restrict__ idx, float* __restrict__ gval, float* __restrict__ gsum,
    unsigned short* __restrict__ wt, float* __restrict__ outz)
{
  __shared__ float bs[4];
  __shared__ unsigned short tile[64][66];
  const int bid = blockIdx.x;

  if (bid < 2048) {
    // ---- gate: logits (fp64 acc), softmax, argmax, gate sums ----
    int wave = threadIdx.x >> 6, lane = threadIdx.x & 63;
    int s = bid * 4 + wave;
    const float4* f4 = (const float4*)(feat + (size_t)s * MDIM);
    double a0 = 0, a1 = 0, a2 = 0, a3 = 0;
    #pragma unroll
    for (int j = 0; j < 4; ++j) {
      int m4 = lane + j * 64;
      float4 x = f4[m4];
      #pragma unroll
      for (int c = 0; c < 4; ++c) {
        float xv = (c == 0) ? x.x : (c == 1) ? x.y : (c == 2) ? x.z : x.w;
        float4 w = ((const float4*)gw)[m4 * 4 + c];
        a0 += (double)xv * w.x; a1 += (double)xv * w.y;
        a2 += (double)xv * w.z; a3 += (double)xv * w.w;
      }
    }
    #pragma unroll
    for (int off = 32; off; off >>= 1) {
      a0 += __shfl_down(a0, off); a1 += __shfl_down(a1, off);
      a2 += __shfl_down(a2, off); a3 += __shfl_down(a3, off);
    }
    if (threadIdx.x < 4) bs[threadIdx.x] = 0.f;
    __syncthreads();
    if (lane == 0) {
      double lg[4] = {a0, a1, a2, a3};
      double mx = lg[0]; int bi = 0;
      #pragma unroll
      for (int e = 1; e < 4; ++e) if (lg[e] > mx) { mx = lg[e]; bi = e; }  // first-max
      float ex[4]; float den = 0.f;
      #pragma unroll
      for (int e = 0; e < 4; ++e) { ex[e] = __expf((float)(lg[e] - mx)); den += ex[e]; }
      float inv = 1.f / den;
      idx[s]  = bi;
      gval[s] = ex[bi] * inv;
      #pragma unroll
      for (int e = 0; e < 4; ++e) atomicAdd(&bs[e], ex[e] * inv);
    }
    __syncthreads();
    if (threadIdx.x < 4) atomicAdd(&gsum[threadIdx.x], bs[threadIdx.x]);
  } else if (bid < 2048 + 4096) {
    // ---- w1 transpose+cast: [1024,4096] f32 -> [4096,1024] bf16, per expert ----
    int t = bid - 2048;
    int bz = t >> 10, rem = t & 1023;
    int bx = rem & 63, by = rem >> 6;          // bx: H/64, by: M/64
    const float* in = w1 + (size_t)bz * MDIM * HDIM;
    unsigned short* out = wt + (size_t)bz * MDIM * HDIM;
    int c0 = bx * 64, r0 = by * 64;
    int tx = threadIdx.x & 15, ty = threadIdx.x >> 4;
    #pragma unroll
    for (int p = 0; p < 4; ++p) {
      int r = ty + p * 16;
      float4 v = *(const float4*)(in + (size_t)(r0 + r) * HDIM + c0 + tx * 4);
      tile[r][tx * 4 + 0] = f2bf(v.x);
      tile[r][tx * 4 + 1] = f2bf(v.y);
      tile[r][tx * 4 + 2] = f2bf(v.z);
      tile[r][tx * 4 + 3] = f2bf(v.w);
    }
    __syncthreads();
    #pragma unroll
    for (int p = 0; p < 4; ++p) {
      int c = ty + p * 16;
      ushort4 o;
      o.x = tile[tx * 4 + 0][c];
      o.y = tile[tx * 4 + 1][c];
      o.z = tile[tx * 4 + 2][c];
      o.w = tile[tx * 4 + 3][c];
      *(ushort4*)(out + (size_t)(c0 + c) * MDIM + r0 + tx * 4) = o;
    }
  } else {
    // ---- zero d_out (S_TOK*ODIM floats): 2048 blocks x 16KB ----
    int t = bid - (2048 + 4096);
    float4* p = (float4*)(outz + (size_t)t * 4096) + threadIdx.x;
    float4 z = {0.f, 0.f, 0.f, 0.f};
    #pragma unroll
    for (int q = 0; q < 4; ++q) p[q * 256] = z;
  }
}

// -------- ordered per-expert rank scan: 16 waves, LDS wave-prefix, l_aux -------
__global__ __launch_bounds__(1024) void scan_kernel(
    const int* __restrict__ idx, int* __restrict__ perm,
    int* __restrict__ ne, const float* __restrict__ gsum,
    float* __restrict__ laux)
{
  const int tid = threadIdx.x, wave = tid >> 6, lane = tid & 63;
  __shared__ int cnt[16][4];
  __shared__ int off[16][4];
  __shared__ int tot[4];
  unsigned long long below = (lane == 0) ? 0ull : ((~0ull) >> (64 - lane));

  int myE[8], loc[8];
  int c[4] = {0, 0, 0, 0};
  #pragma unroll
  for (int j = 0; j < 8; ++j) {
    int s = wave * 512 + j * 64 + lane;
    int ev = idx[s];
    myE[j] = ev;
    #pragma unroll
    for (int e = 0; e < 4; ++e) {
      unsigned long long mb = __ballot(ev == e);
      if (ev == e) loc[j] = c[e] + __popcll(mb & below);
      c[e] += __popcll(mb);   // wave-uniform
    }
  }
  if (lane == 0) {
    #pragma unroll
    for (int e = 0; e < 4; ++e) cnt[wave][e] = c[e];
  }
  __syncthreads();
  if (tid < 64) {            // 16 waves x 4 experts
    int w = tid >> 2, e = tid & 3;
    int o = 0;
    for (int w2 = 0; w2 < 16; ++w2) if (w2 < w) o += cnt[w2][e];
    off[w][e] = o;
    if (w == 15) tot[e] = o + cnt[15][e];
  }
  __syncthreads();
  #pragma unroll
  for (int j = 0; j < 8; ++j) {
    int s = wave * 512 + j * 64 + lane;
    int e = myE[j];
    int rank = off[wave][e] + loc[j];
    if (rank < CAP) perm[e * CAP + rank] = s;   // dropped tokens: no slot
  }
  if (tid < 4) ne[tid] = tot[tid] < CAP ? tot[tid] : CAP;
  if (tid == 0) {   // l_aux: PRE-capacity counts x full softmax means
    float l = 0.f;
    #pragma unroll
    for (int e = 0; e < 4; ++e)
      l += (gsum[e] * (1.0f / S_TOK)) * ((float)tot[e] * (1.0f / S_TOK));
    *laux = l * (float)NEXP;
  }
}

// ---------------- cast + transpose weights: [R,C] f32 -> [C,R] bf16 ------------
__global__ __launch_bounds__(256) void transpose_cast(
    const float* __restrict__ in, unsigned short* __restrict__ out, int R, int Cc)
{
  __shared__ unsigned short tile[64][66];
  in  += (size_t)blockIdx.z * R * Cc;
  out += (size_t)blockIdx.z * R * Cc;
  int c0 = blockIdx.x * 64, r0 = blockIdx.y * 64;
  int tx = threadIdx.x & 15;
  int ty = threadIdx.x >> 4;
  #pragma unroll
  for (int p = 0; p < 4; ++p) {
    int r = ty + p * 16;
    float4 v = *(const float4*)(in + (size_t)(r0 + r) * Cc + c0 + tx * 4);
    tile[r][tx * 4 + 0] = f2bf(v.x);
    tile[r][tx * 4 + 1] = f2bf(v.y);
    tile[r][tx * 4 + 2] = f2bf(v.z);
    tile[r][tx * 4 + 3] = f2bf(v.w);
  }
  __syncthreads();
  #pragma unroll
  for (int p = 0; p < 4; ++p) {
    int c = ty + p * 16;
    ushort4 o;
    o.x = tile[tx * 4 + 0][c];
    o.y = tile[tx * 4 + 1][c];
    o.z = tile[tx * 4 + 2][c];
    o.w = tile[tx * 4 + 3][c];
    *(ushort4*)(out + (size_t)(c0 + c) * R + r0 + tx * 4) = o;
  }
}

// ---------------- gather kept tokens -> bf16 dispatch buffer -------------------
__global__ __launch_bounds__(256) void gather_kernel(
    const float* __restrict__ feat, const int* __restrict__ perm,
    const int* __restrict__ ne, unsigned short* __restrict__ disp)
{
  int b = blockIdx.x;
  int e = b >> 11, c = b & (CAP - 1);
  int m = threadIdx.x * 4;
  ushort4 o;
  if (c < ne[e]) {
    int s = perm[b];
    float4 v = *(const float4*)(feat + (size_t)s * MDIM + m);
    o.x = f2bf(v.x); o.y = f2bf(v.y); o.z = f2bf(v.z); o.w = f2bf(v.w);
  } else {
    o.x = o.y = o.z = o.w = 0;   // empty slot -> zero row (h row = gelu(0)=0)
  }
  *(ushort4*)(disp + (size_t)b * MDIM + m) = o;
}

// ---------------- fc1: disp[E*C,1024] @ w1t[E,4096,1024] -> gelu -> h bf16 -----
// R4 config (best known): 3D grid, triple-buffer counted-vmcnt pipeline,
// LDS source-swizzle (conflicts = 0), swapped MFMA (D^T) -> ushort4 stores.
// R6: + setprio around the MFMA cluster (T5; pipeline has wave role-split).
__global__ __launch_bounds__(256) void fc1_kernel(
    const unsigned short* __restrict__ A, const unsigned short* __restrict__ Bt,
    const float* __restrict__ b1, unsigned short* __restrict__ Hb)
{
  const int nb = blockIdx.x, mb = blockIdx.y, e = blockIdx.z;
  const int tid = threadIdx.x, wave = tid >> 6, lane = tid & 63;

  __shared__ __align__(16) unsigned short smA[3 * 128 * 32];  // 3 x 8 KB
  __shared__ __align__(16) unsigned short smB[3 * 128 * 32];  // 3 x 8 KB

  const char* Ag = (const char*)(A + ((size_t)e * CAP + (size_t)mb * 128) * MDIM);
  const char* Bg = (const char*)(Bt + ((size_t)e * HDIM + (size_t)nb * 128) * MDIM);

  const int boff0 = (wave * 2 + 0) * 1024 + lane * 16;   // linear byte in 8KB tile
  const int boff1 = (wave * 2 + 1) * 1024 + lane * 16;
  const char* agp0 = stage_src(Ag, boff0, 2048);
  const char* agp1 = stage_src(Ag, boff1, 2048);
  const char* bgp0 = stage_src(Bg, boff0, 2048);
  const char* bgp1 = stage_src(Bg, boff1, 2048);
  const int ldsw0 = (wave * 2 + 0) * 512;   // shorts
  const int ldsw1 = (wave * 2 + 1) * 512;

  const int wm = (wave & 1) * 64, wn = (wave >> 1) * 64;
  const int fr = lane & 15, fq = lane >> 4;
  const int sqA = ((fq ^ ((wm + fr) >> 1)) & 3) * 8;   // swizzled 16B slot (shorts)
  const int sqB = ((fq ^ ((wn + fr) >> 1)) & 3) * 8;

  floatx4 acc[4][4] = {};

  const int NT = MDIM / 32;                 // 32 K-tiles
  int c0 = 0, c1 = 1, c2 = 2;

  gl_lds16(agp0 + 0,  smA + 0 * 4096 + ldsw0);
  gl_lds16(agp1 + 0,  smA + 0 * 4096 + ldsw1);
  gl_lds16(bgp0 + 0,  smB + 0 * 4096 + ldsw0);
  gl_lds16(bgp1 + 0,  smB + 0 * 4096 + ldsw1);
  gl_lds16(agp0 + 64, smA + 1 * 4096 + ldsw0);
  gl_lds16(agp1 + 64, smA + 1 * 4096 + ldsw1);
  gl_lds16(bgp0 + 64, smB + 1 * 4096 + ldsw0);
  gl_lds16(bgp1 + 64, smB + 1 * 4096 + ldsw1);
  asm volatile("s_waitcnt vmcnt(4)" ::: "memory");
  __builtin_amdgcn_s_barrier();

  for (int kt = 0; kt < NT; ++kt) {
    if (kt + 2 < NT) {
      int kb = (kt + 2) * 64;
      gl_lds16(agp0 + kb, smA + c2 * 4096 + ldsw0);
      gl_lds16(agp1 + kb, smA + c2 * 4096 + ldsw1);
      gl_lds16(bgp0 + kb, smB + c2 * 4096 + ldsw0);
      gl_lds16(bgp1 + kb, smB + c2 * 4096 + ldsw1);
    }
    const unsigned short* sA = smA + c0 * 4096;
    const unsigned short* sB = smB + c0 * 4096;
    short8 af[4], bfr[4];
    #pragma unroll
    for (int i = 0; i < 4; ++i)
      af[i] = *(const short8*)&sA[(wm + i * 16 + fr) * 32 + sqA];
    #pragma unroll
    for (int j = 0; j < 4; ++j)
      bfr[j] = *(const short8*)&sB[(wn + j * 16 + fr) * 32 + sqB];
    __builtin_amdgcn_s_setprio(1);
    #pragma unroll
    for (int i = 0; i < 4; ++i)
      #pragma unroll
      for (int j = 0; j < 4; ++j)   // swapped operands: acc = D^T
        acc[i][j] = __builtin_amdgcn_mfma_f32_16x16x32_bf16(bfr[j], af[i], acc[i][j], 0, 0, 0);
    __builtin_amdgcn_s_setprio(0);
    if (kt + 1 < NT) {
      if (kt + 2 < NT) asm volatile("s_waitcnt vmcnt(4)" ::: "memory");
      else             asm volatile("s_waitcnt vmcnt(0)" ::: "memory");
      __builtin_amdgcn_s_barrier();
    }
    int t = c0; c0 = c1; c1 = c2; c2 = t;
  }

  // D^T layout: value(i,j,r) at m = wm+i*16+fr, n = wn+j*16+fq*4+r
  unsigned short* Hrow = Hb + (size_t)e * CAP * HDIM;
  #pragma unroll
  for (int j = 0; j < 4; ++j) {
    int gn0 = nb * 128 + wn + j * 16 + fq * 4;
    float4 bv = *(const float4*)&b1[e * HDIM + gn0];
    #pragma unroll
    for (int i = 0; i < 4; ++i) {
      int m = mb * 128 + wm + i * 16 + fr;
      ushort4 o;
      o.x = f2bf(gelu_tanh(acc[i][j][0] + bv.x));
      o.y = f2bf(gelu_tanh(acc[i][j][1] + bv.y));
      o.z = f2bf(gelu_tanh(acc[i][j][2] + bv.z));
      o.w = f2bf(gelu_tanh(acc[i][j][3] + bv.w));
      *(ushort4*)&Hrow[(size_t)m * HDIM + gn0] = o;
    }
  }
}

// ---------------- fc2: h[E*C,4096] @ w2t[E,1024,4096] -> gated scatter ---------
// R4 config (best known: BM=64, 117 us): triple-buffer + vmcnt(3) + XCD-chunk
// + source-swizzle + D^T float4 epilogue.  R6: + setprio (T5).
__global__ __launch_bounds__(256) void fc2_kernel(
    const unsigned short* __restrict__ A, const unsigned short* __restrict__ Bt,
    const float* __restrict__ b2, const int* __restrict__ perm,
    const int* __restrict__ ne, const float* __restrict__ gval,
    float* __restrict__ out)
{
  const int b = blockIdx.x;                    // 0..1023
  const int wg = (b & 7) * 128 + (b >> 3);
  const int nb = wg & 7, mb = (wg >> 3) & 31, e = wg >> 8;
  const int tid = threadIdx.x, wave = tid >> 6, lane = tid & 63;

  __shared__ __align__(16) unsigned short smA[3 * 64 * 32];    // 3 x 4 KB
  __shared__ __align__(16) unsigned short smB[3 * 128 * 32];   // 3 x 8 KB

  const char* Ag = (const char*)(A + ((size_t)e * CAP + (size_t)mb * 64) * HDIM);
  const char* Bg = (const char*)(Bt + ((size_t)e * ODIM + (size_t)nb * 128) * HDIM);

  // A: one 16B DMA per thread covers the 64x32 tile
  const char* agp = stage_src(Ag, tid * 16, 8192);
  // B: two 16B DMAs per thread
  const int boff0 = (wave * 2 + 0) * 1024 + lane * 16;
  const int boff1 = (wave * 2 + 1) * 1024 + lane * 16;
  const char* bgp0 = stage_src(Bg, boff0, 8192);
  const char* bgp1 = stage_src(Bg, boff1, 8192);

  const int ldsA_w = wave * 512;               // shorts
  const int ldsB_w0 = (wave * 2 + 0) * 512;
  const int ldsB_w1 = (wave * 2 + 1) * 512;

  const int wm = (wave & 1) * 32, wn = (wave >> 1) * 64;
  const int fr = lane & 15, fq = lane >> 4;
  const int sqA = ((fq ^ ((wm + fr) >> 1)) & 3) * 8;
  const int sqB = ((fq ^ ((wn + fr) >> 1)) & 3) * 8;

  floatx4 acc[2][4] = {};

  const int NT = HDIM / 32;                    // 128 K-tiles
  int c0 = 0, c1 = 1, c2 = 2;

  gl_lds16(agp + 0 * 64,  smA + 0 * 2048 + ldsA_w);
  gl_lds16(bgp0 + 0 * 64, smB + 0 * 4096 + ldsB_w0);
  gl_lds16(bgp1 + 0 * 64, smB + 0 * 4096 + ldsB_w1);
  gl_lds16(agp + 1 * 64,  smA + 1 * 2048 + ldsA_w);
  gl_lds16(bgp0 + 1 * 64, smB + 1 * 4096 + ldsB_w0);
  gl_lds16(bgp1 + 1 * 64, smB + 1 * 4096 + ldsB_w1);
  asm volatile("s_waitcnt vmcnt(3)" ::: "memory");
  __builtin_amdgcn_s_barrier();

  for (int kt = 0; kt < NT; ++kt) {
    if (kt + 2 < NT) {
      int kb = (kt + 2) * 64;
      gl_lds16(agp + kb,  smA + c2 * 2048 + ldsA_w);
      gl_lds16(bgp0 + kb, smB + c2 * 4096 + ldsB_w0);
      gl_lds16(bgp1 + kb, smB + c2 * 4096 + ldsB_w1);
    }
    const unsigned short* sA = smA + c0 * 2048;
    const unsigned short* sB = smB + c0 * 4096;
    short8 af[2], bfr[4];
    #pragma unroll
    for (int i = 0; i < 2; ++i)
      af[i] = *(const short8*)&sA[(wm + i * 16 + fr) * 32 + sqA];
    #pragma unroll
    for (int j = 0; j < 4; ++j)
      bfr[j] = *(const short8*)&sB[(wn + j * 16 + fr) * 32 + sqB];
    __builtin_amdgcn_s_setprio(1);
    #pragma unroll
    for (int i = 0; i < 2; ++i)
      #pragma unroll
      for (int j = 0; j < 4; ++j)   // swapped operands: acc = D^T
        acc[i][j] = __builtin_amdgcn_mfma_f32_16x16x32_bf16(bfr[j], af[i], acc[i][j], 0, 0, 0);
    __builtin_amdgcn_s_setprio(0);
    if (kt + 1 < NT) {
      if (kt + 2 < NT) asm volatile("s_waitcnt vmcnt(3)" ::: "memory");
      else             asm volatile("s_waitcnt vmcnt(0)" ::: "memory");
      __builtin_amdgcn_s_barrier();
    }
    int t = c0; c0 = c1; c1 = c2; c2 = t;
  }

  // D^T: value(i,j,r) at token-slot c = mb*64+wm+i*16+fr, n = wn+j*16+fq*4+r
  const int nE = ne[e];
  float4 b2v[4];
  #pragma unroll
  for (int j = 0; j < 4; ++j)
    b2v[j] = *(const float4*)&b2[e * ODIM + nb * 128 + wn + j * 16 + fq * 4];
  #pragma unroll
  for (int i = 0; i < 2; ++i) {
    int c = mb * 64 + wm + i * 16 + fr;
    if (c < nE) {
      int s = perm[e * CAP + c];
      float g = gval[s];
      float* orow = out + (size_t)s * ODIM + nb * 128 + wn + fq * 4;
      #pragma unroll
      for (int j = 0; j < 4; ++j) {
        float4 o;
        o.x = (acc[i][j][0] + b2v[j].x) * g;
        o.y = (acc[i][j][1] + b2v[j].y) * g;
        o.z = (acc[i][j][2] + b2v[j].z) * g;
        o.w = (acc[i][j][3] + b2v[j].w) * g;
        *(float4*)&orow[j * 16] = o;
      }
    }
  }
}

// ------------------------------- launch ---------------------------------------
extern "C" void kernel_launch(void* const* d_in, const int* in_sizes, int n_in,
                              void* d_out, int out_size, void* d_ws, size_t ws_size,
                              hipStream_t stream) {
  const float* feat = (const float*)d_in[0];
  const float* gw   = (const float*)d_in[1];
  const float* w1   = (const float*)d_in[2];
  const float* b1   = (const float*)d_in[3];
  const float* w2   = (const float*)d_in[4];
  const float* b2   = (const float*)d_in[5];
  float* out = (float*)d_out;

  char* ws = (char*)d_ws;
  unsigned short* wt   = (unsigned short*)(ws);                  // 33,554,432 B
  unsigned short* hbuf = (unsigned short*)(ws + 33554432);       // 67,108,864 B
  unsigned short* disp = (unsigned short*)(ws + 100663296);      // 16,777,216 B
  int*   idx  = (int*)  (ws + 117440512);
  float* gval = (float*)(ws + 117473280);
  int*   perm = (int*)  (ws + 117506048);
  float* gsum = (float*)(ws + 117538816);
  int*   ne   = (int*)  (ws + 117538832);

  hipMemsetAsync(ws + 117538816, 0, 32, stream);

  // prep = gate (2048) + w1 transpose (4096) + d_out zero (2048)
  prep_kernel<<<2048 + 4096 + 2048, 256, 0, stream>>>(
      feat, gw, w1, idx, gval, gsum, wt, out);
  scan_kernel<<<1, 1024, 0, stream>>>(idx, perm, ne, gsum, out + (size_t)S_TOK * ODIM);
  gather_kernel<<<NEXP * CAP, 256, 0, stream>>>(feat, perm, ne, disp);
  fc1_kernel<<<dim3(HDIM / 128, CAP / 128, NEXP), 256, 0, stream>>>(disp, wt, b1, hbuf);
  transpose_cast<<<dim3(ODIM / 64, HDIM / 64, NEXP), 256, 0, stream>>>(w2, wt, HDIM, ODIM);
  fc2_kernel<<<1024, 256, 0, stream>>>(hbuf, wt, b2, perm, ne, gval, out);
}

// Round 7
// 416.309 us; speedup vs baseline: 1.0611x; 1.0072x over previous
//
#include <hip/hip_runtime.h>
#include <stdint.h>

#define S_TOK 8192
#define MDIM  1024
#define HDIM  4096
#define ODIM  1024
#define NEXP  4
#define CAP   2048   // ceil(S/E)

typedef __attribute__((ext_vector_type(8))) short short8;
typedef __attribute__((ext_vector_type(4))) float floatx4;

__device__ __forceinline__ unsigned short f2bf(float x) {
  union { float f; unsigned u; } v; v.f = x;
  unsigned r = v.u + 0x7FFFu + ((v.u >> 16) & 1u);   // RNE
  return (unsigned short)(r >> 16);
}

__device__ __forceinline__ void gl_lds16(const void* g, void* l) {
  __builtin_amdgcn_global_load_lds(
      (const __attribute__((address_space(1))) void*)g,
      (__attribute__((address_space(3))) void*)l, 16, 0, 0);
}

// gelu(x) = 0.5x(1+tanh(z)) = x * sigmoid(2z), z = 0.79788456(x + 0.044715 x^3)
__device__ __forceinline__ float gelu_tanh(float x) {
  float p = x * x;
  float t = x * (1.5957691216f + 0.0713548353f * p);   // 2z
  float E = __expf(-t);
  return __fdividef(x, 1.0f + E);
}

// Swizzled staging source: LDS slot s (of 4 per 64B row) receives row element
// c16 = s ^ ((row>>1)&3).  Reads use the same XOR -> 8-way bank conflict
// becomes 2-way (free).  LDS itself stays linear (global_load_lds constraint).
__device__ __forceinline__ const char* stage_src(const char* base, int linoff,
                                                 int rowstride) {
  int row  = linoff >> 6;
  int slot = (linoff >> 4) & 3;
  int c16  = slot ^ ((row >> 1) & 3);
  return base + (size_t)row * rowstride + (c16 << 4);
}

// ---------------- prep: gate + w1 transpose + d_out zero, one launch ----------
__global__ __launch_bounds__(256) void prep_kernel(
    const float* __restrict__ feat, const float* __restrict__ gw,
    const float* __restrict__ w1,
    int* __restrict__ idx, float* __restrict__ gval, float* __restrict__ gsum,
    unsigned short* __restrict__ wt, float* __restrict__ outz)
{
  __shared__ float bs[4];
  __shared__ unsigned short tile[64][66];
  const int bid = blockIdx.x;

  if (bid < 2048) {
    // ---- gate: logits (fp64 acc), softmax, argmax, gate sums ----
    int wave = threadIdx.x >> 6, lane = threadIdx.x & 63;
    int s = bid * 4 + wave;
    const float4* f4 = (const float4*)(feat + (size_t)s * MDIM);
    double a0 = 0, a1 = 0, a2 = 0, a3 = 0;
    #pragma unroll
    for (int j = 0; j < 4; ++j) {
      int m4 = lane + j * 64;
      float4 x = f4[m4];
      #pragma unroll
      for (int c = 0; c < 4; ++c) {
        float xv = (c == 0) ? x.x : (c == 1) ? x.y : (c == 2) ? x.z : x.w;
        float4 w = ((const float4*)gw)[m4 * 4 + c];
        a0 += (double)xv * w.x; a1 += (double)xv * w.y;
        a2 += (double)xv * w.z; a3 += (double)xv * w.w;
      }
    }
    #pragma unroll
    for (int off = 32; off; off >>= 1) {
      a0 += __shfl_down(a0, off); a1 += __shfl_down(a1, off);
      a2 += __shfl_down(a2, off); a3 += __shfl_down(a3, off);
    }
    if (threadIdx.x < 4) bs[threadIdx.x] = 0.f;
    __syncthreads();
    if (lane == 0) {
      double lg[4] = {a0, a1, a2, a3};
      double mx = lg[0]; int bi = 0;
      #pragma unroll
      for (int e = 1; e < 4; ++e) if (lg[e] > mx) { mx = lg[e]; bi = e; }  // first-max
      float ex[4]; float den = 0.f;
      #pragma unroll
      for (int e = 0; e < 4; ++e) { ex[e] = __expf((float)(lg[e] - mx)); den += ex[e]; }
      float inv = 1.f / den;
      idx[s]  = bi;
      gval[s] = ex[bi] * inv;
      #pragma unroll
      for (int e = 0; e < 4; ++e) atomicAdd(&bs[e], ex[e] * inv);
    }
    __syncthreads();
    if (threadIdx.x < 4) atomicAdd(&gsum[threadIdx.x], bs[threadIdx.x]);
  } else if (bid < 2048 + 4096) {
    // ---- w1 transpose+cast: [1024,4096] f32 -> [4096,1024] bf16, per expert ----
    int t = bid - 2048;
    int bz = t >> 10, rem = t & 1023;
    int bx = rem & 63, by = rem >> 6;          // bx: H/64, by: M/64
    const float* in = w1 + (size_t)bz * MDIM * HDIM;
    unsigned short* out = wt + (size_t)bz * MDIM * HDIM;
    int c0 = bx * 64, r0 = by * 64;
    int tx = threadIdx.x & 15, ty = threadIdx.x >> 4;
    #pragma unroll
    for (int p = 0; p < 4; ++p) {
      int r = ty + p * 16;
      float4 v = *(const float4*)(in + (size_t)(r0 + r) * HDIM + c0 + tx * 4);
      tile[r][tx * 4 + 0] = f2bf(v.x);
      tile[r][tx * 4 + 1] = f2bf(v.y);
      tile[r][tx * 4 + 2] = f2bf(v.z);
      tile[r][tx * 4 + 3] = f2bf(v.w);
    }
    __syncthreads();
    #pragma unroll
    for (int p = 0; p < 4; ++p) {
      int c = ty + p * 16;
      ushort4 o;
      o.x = tile[tx * 4 + 0][c];
      o.y = tile[tx * 4 + 1][c];
      o.z = tile[tx * 4 + 2][c];
      o.w = tile[tx * 4 + 3][c];
      *(ushort4*)(out + (size_t)(c0 + c) * MDIM + r0 + tx * 4) = o;
    }
  } else {
    // ---- zero d_out (S_TOK*ODIM floats): 2048 blocks x 16KB ----
    int t = bid - (2048 + 4096);
    float4* p = (float4*)(outz + (size_t)t * 4096) + threadIdx.x;
    float4 z = {0.f, 0.f, 0.f, 0.f};
    #pragma unroll
    for (int q = 0; q < 4; ++q) p[q * 256] = z;
  }
}

// -------- ordered per-expert rank scan: 16 waves, LDS wave-prefix, l_aux -------
__global__ __launch_bounds__(1024) void scan_kernel(
    const int* __restrict__ idx, int* __restrict__ perm,
    int* __restrict__ ne, const float* __restrict__ gsum,
    float* __restrict__ laux)
{
  const int tid = threadIdx.x, wave = tid >> 6, lane = tid & 63;
  __shared__ int cnt[16][4];
  __shared__ int off[16][4];
  __shared__ int tot[4];
  unsigned long long below = (lane == 0) ? 0ull : ((~0ull) >> (64 - lane));

  int myE[8], loc[8];
  int c[4] = {0, 0, 0, 0};
  #pragma unroll
  for (int j = 0; j < 8; ++j) {
    int s = wave * 512 + j * 64 + lane;
    int ev = idx[s];
    myE[j] = ev;
    #pragma unroll
    for (int e = 0; e < 4; ++e) {
      unsigned long long mb = __ballot(ev == e);
      if (ev == e) loc[j] = c[e] + __popcll(mb & below);
      c[e] += __popcll(mb);   // wave-uniform
    }
  }
  if (lane == 0) {
    #pragma unroll
    for (int e = 0; e < 4; ++e) cnt[wave][e] = c[e];
  }
  __syncthreads();
  if (tid < 64) {            // 16 waves x 4 experts
    int w = tid >> 2, e = tid & 3;
    int o = 0;
    for (int w2 = 0; w2 < 16; ++w2) if (w2 < w) o += cnt[w2][e];
    off[w][e] = o;
    if (w == 15) tot[e] = o + cnt[15][e];
  }
  __syncthreads();
  #pragma unroll
  for (int j = 0; j < 8; ++j) {
    int s = wave * 512 + j * 64 + lane;
    int e = myE[j];
    int rank = off[wave][e] + loc[j];
    if (rank < CAP) perm[e * CAP + rank] = s;   // dropped tokens: no slot
  }
  if (tid < 4) ne[tid] = tot[tid] < CAP ? tot[tid] : CAP;
  if (tid == 0) {   // l_aux: PRE-capacity counts x full softmax means
    float l = 0.f;
    #pragma unroll
    for (int e = 0; e < 4; ++e)
      l += (gsum[e] * (1.0f / S_TOK)) * ((float)tot[e] * (1.0f / S_TOK));
    *laux = l * (float)NEXP;
  }
}

// ---------------- cast + transpose weights: [R,C] f32 -> [C,R] bf16 ------------
__global__ __launch_bounds__(256) void transpose_cast(
    const float* __restrict__ in, unsigned short* __restrict__ out, int R, int Cc)
{
  __shared__ unsigned short tile[64][66];
  in  += (size_t)blockIdx.z * R * Cc;
  out += (size_t)blockIdx.z * R * Cc;
  int c0 = blockIdx.x * 64, r0 = blockIdx.y * 64;
  int tx = threadIdx.x & 15;
  int ty = threadIdx.x >> 4;
  #pragma unroll
  for (int p = 0; p < 4; ++p) {
    int r = ty + p * 16;
    float4 v = *(const float4*)(in + (size_t)(r0 + r) * Cc + c0 + tx * 4);
    tile[r][tx * 4 + 0] = f2bf(v.x);
    tile[r][tx * 4 + 1] = f2bf(v.y);
    tile[r][tx * 4 + 2] = f2bf(v.z);
    tile[r][tx * 4 + 3] = f2bf(v.w);
  }
  __syncthreads();
  #pragma unroll
  for (int p = 0; p < 4; ++p) {
    int c = ty + p * 16;
    ushort4 o;
    o.x = tile[tx * 4 + 0][c];
    o.y = tile[tx * 4 + 1][c];
    o.z = tile[tx * 4 + 2][c];
    o.w = tile[tx * 4 + 3][c];
    *(ushort4*)(out + (size_t)(c0 + c) * R + r0 + tx * 4) = o;
  }
}

// ---------------- gather kept tokens -> bf16 dispatch buffer -------------------
__global__ __launch_bounds__(256) void gather_kernel(
    const float* __restrict__ feat, const int* __restrict__ perm,
    const int* __restrict__ ne, unsigned short* __restrict__ disp)
{
  int b = blockIdx.x;
  int e = b >> 11, c = b & (CAP - 1);
  int m = threadIdx.x * 4;
  ushort4 o;
  if (c < ne[e]) {
    int s = perm[b];
    float4 v = *(const float4*)(feat + (size_t)s * MDIM + m);
    o.x = f2bf(v.x); o.y = f2bf(v.y); o.z = f2bf(v.z); o.w = f2bf(v.w);
  } else {
    o.x = o.y = o.z = o.w = 0;   // empty slot -> zero row (h row = gelu(0)=0)
  }
  *(ushort4*)(disp + (size_t)b * MDIM + m) = o;
}

// ---------------- fc1: disp[E*C,1024] @ w1t[E,4096,1024] -> gelu -> h bf16 -----
// R7: setprio REMOVED (R6 A/B: -21% on this barrier-locked schedule, T5 regime
// gate).  K-loop hand-unrolled x3 -> static buffer offsets (rule #20): kills
// the runtime rotation's per-iter address VALU.  Sync structure unchanged.
__global__ __launch_bounds__(256) void fc1_kernel(
    const unsigned short* __restrict__ A, const unsigned short* __restrict__ Bt,
    const float* __restrict__ b1, unsigned short* __restrict__ Hb)
{
  const int nb = blockIdx.x, mb = blockIdx.y, e = blockIdx.z;
  const int tid = threadIdx.x, wave = tid >> 6, lane = tid & 63;

  __shared__ __align__(16) unsigned short smA[3 * 128 * 32];  // 3 x 8 KB
  __shared__ __align__(16) unsigned short smB[3 * 128 * 32];  // 3 x 8 KB

  const char* Ag = (const char*)(A + ((size_t)e * CAP + (size_t)mb * 128) * MDIM);
  const char* Bg = (const char*)(Bt + ((size_t)e * HDIM + (size_t)nb * 128) * MDIM);

  const int boff0 = (wave * 2 + 0) * 1024 + lane * 16;   // linear byte in 8KB tile
  const int boff1 = (wave * 2 + 1) * 1024 + lane * 16;
  const char* agp0 = stage_src(Ag, boff0, 2048);
  const char* agp1 = stage_src(Ag, boff1, 2048);
  const char* bgp0 = stage_src(Bg, boff0, 2048);
  const char* bgp1 = stage_src(Bg, boff1, 2048);
  const int ldsw0 = (wave * 2 + 0) * 512;   // shorts
  const int ldsw1 = (wave * 2 + 1) * 512;

  const int wm = (wave & 1) * 64, wn = (wave >> 1) * 64;
  const int fr = lane & 15, fq = lane >> 4;
  const int sqA = ((fq ^ ((wm + fr) >> 1)) & 3) * 8;   // swizzled 16B slot (shorts)
  const int sqB = ((fq ^ ((wn + fr) >> 1)) & 3) * 8;

  floatx4 acc[4][4] = {};

  auto stage = [&](int kb, int bo) {
    gl_lds16(agp0 + kb, smA + bo + ldsw0);
    gl_lds16(agp1 + kb, smA + bo + ldsw1);
    gl_lds16(bgp0 + kb, smB + bo + ldsw0);
    gl_lds16(bgp1 + kb, smB + bo + ldsw1);
  };
  auto comp = [&](const unsigned short* sA, const unsigned short* sB) {
    short8 af[4], bfr[4];
    #pragma unroll
    for (int i = 0; i < 4; ++i)
      af[i] = *(const short8*)&sA[(wm + i * 16 + fr) * 32 + sqA];
    #pragma unroll
    for (int j = 0; j < 4; ++j)
      bfr[j] = *(const short8*)&sB[(wn + j * 16 + fr) * 32 + sqB];
    #pragma unroll
    for (int i = 0; i < 4; ++i)
      #pragma unroll
      for (int j = 0; j < 4; ++j)   // swapped operands: acc = D^T
        acc[i][j] = __builtin_amdgcn_mfma_f32_16x16x32_bf16(bfr[j], af[i], acc[i][j], 0, 0, 0);
  };

  const int NT = MDIM / 32;                 // 32 K-tiles; NT-2 = 30 = 3*10
  stage(0, 0); stage(64, 4096);
  asm volatile("s_waitcnt vmcnt(4)" ::: "memory");
  __builtin_amdgcn_s_barrier();

  for (int kt = 0; kt < NT - 2; kt += 3) {
    stage((kt + 2) * 64, 2 * 4096); comp(smA, smB);
    asm volatile("s_waitcnt vmcnt(4)" ::: "memory"); __builtin_amdgcn_s_barrier();
    stage((kt + 3) * 64, 0 * 4096); comp(smA + 4096, smB + 4096);
    asm volatile("s_waitcnt vmcnt(4)" ::: "memory"); __builtin_amdgcn_s_barrier();
    stage((kt + 4) * 64, 1 * 4096); comp(smA + 8192, smB + 8192);
    asm volatile("s_waitcnt vmcnt(4)" ::: "memory"); __builtin_amdgcn_s_barrier();
  }
  comp(smA, smB);                           // tile NT-2 (buf0: 30%3==0)
  asm volatile("s_waitcnt vmcnt(0)" ::: "memory");
  __builtin_amdgcn_s_barrier();
  comp(smA + 4096, smB + 4096);             // tile NT-1 (buf1)

  // D^T layout: value(i,j,r) at m = wm+i*16+fr, n = wn+j*16+fq*4+r
  unsigned short* Hrow = Hb + (size_t)e * CAP * HDIM;
  #pragma unroll
  for (int j = 0; j < 4; ++j) {
    int gn0 = nb * 128 + wn + j * 16 + fq * 4;
    float4 bv = *(const float4*)&b1[e * HDIM + gn0];
    #pragma unroll
    for (int i = 0; i < 4; ++i) {
      int m = mb * 128 + wm + i * 16 + fr;
      ushort4 o;
      o.x = f2bf(gelu_tanh(acc[i][j][0] + bv.x));
      o.y = f2bf(gelu_tanh(acc[i][j][1] + bv.y));
      o.z = f2bf(gelu_tanh(acc[i][j][2] + bv.z));
      o.w = f2bf(gelu_tanh(acc[i][j][3] + bv.w));
      *(ushort4*)&Hrow[(size_t)m * HDIM + gn0] = o;
    }
  }
}

// ---------------- fc2: h[E*C,4096] @ w2t[E,1024,4096] -> gated scatter ---------
// R7: setprio removed; K-loop hand-unrolled x3 (static buffer offsets).
// Otherwise R4 best-known: BM=64, triple-buffer vmcnt(3), XCD-chunk, swizzle,
// D^T float4 epilogue.
__global__ __launch_bounds__(256) void fc2_kernel(
    const unsigned short* __restrict__ A, const unsigned short* __restrict__ Bt,
    const float* __restrict__ b2, const int* __restrict__ perm,
    const int* __restrict__ ne, const float* __restrict__ gval,
    float* __restrict__ out)
{
  const int b = blockIdx.x;                    // 0..1023
  const int wg = (b & 7) * 128 + (b >> 3);
  const int nb = wg & 7, mb = (wg >> 3) & 31, e = wg >> 8;
  const int tid = threadIdx.x, wave = tid >> 6, lane = tid & 63;

  __shared__ __align__(16) unsigned short smA[3 * 64 * 32];    // 3 x 4 KB
  __shared__ __align__(16) unsigned short smB[3 * 128 * 32];   // 3 x 8 KB

  const char* Ag = (const char*)(A + ((size_t)e * CAP + (size_t)mb * 64) * HDIM);
  const char* Bg = (const char*)(Bt + ((size_t)e * ODIM + (size_t)nb * 128) * HDIM);

  // A: one 16B DMA per thread covers the 64x32 tile
  const char* agp = stage_src(Ag, tid * 16, 8192);
  // B: two 16B DMAs per thread
  const int boff0 = (wave * 2 + 0) * 1024 + lane * 16;
  const int boff1 = (wave * 2 + 1) * 1024 + lane * 16;
  const char* bgp0 = stage_src(Bg, boff0, 8192);
  const char* bgp1 = stage_src(Bg, boff1, 8192);

  const int ldsA_w = wave * 512;               // shorts
  const int ldsB_w0 = (wave * 2 + 0) * 512;
  const int ldsB_w1 = (wave * 2 + 1) * 512;

  const int wm = (wave & 1) * 32, wn = (wave >> 1) * 64;
  const int fr = lane & 15, fq = lane >> 4;
  const int sqA = ((fq ^ ((wm + fr) >> 1)) & 3) * 8;
  const int sqB = ((fq ^ ((wn + fr) >> 1)) & 3) * 8;

  floatx4 acc[2][4] = {};

  auto stage = [&](int kb, int boA, int boB) {
    gl_lds16(agp + kb,  smA + boA + ldsA_w);
    gl_lds16(bgp0 + kb, smB + boB + ldsB_w0);
    gl_lds16(bgp1 + kb, smB + boB + ldsB_w1);
  };
  auto comp = [&](const unsigned short* sA, const unsigned short* sB) {
    short8 af[2], bfr[4];
    #pragma unroll
    for (int i = 0; i < 2; ++i)
      af[i] = *(const short8*)&sA[(wm + i * 16 + fr) * 32 + sqA];
    #pragma unroll
    for (int j = 0; j < 4; ++j)
      bfr[j] = *(const short8*)&sB[(wn + j * 16 + fr) * 32 + sqB];
    #pragma unroll
    for (int i = 0; i < 2; ++i)
      #pragma unroll
      for (int j = 0; j < 4; ++j)   // swapped operands: acc = D^T
        acc[i][j] = __builtin_amdgcn_mfma_f32_16x16x32_bf16(bfr[j], af[i], acc[i][j], 0, 0, 0);
  };

  const int NT = HDIM / 32;                    // 128 K-tiles; NT-2 = 126 = 3*42
  stage(0, 0, 0); stage(64, 2048, 4096);
  asm volatile("s_waitcnt vmcnt(3)" ::: "memory");
  __builtin_amdgcn_s_barrier();

  for (int kt = 0; kt < NT - 2; kt += 3) {
    stage((kt + 2) * 64, 2 * 2048, 2 * 4096); comp(smA, smB);
    asm volatile("s_waitcnt vmcnt(3)" ::: "memory"); __builtin_amdgcn_s_barrier();
    stage((kt + 3) * 64, 0 * 2048, 0 * 4096); comp(smA + 2048, smB + 4096);
    asm volatile("s_waitcnt vmcnt(3)" ::: "memory"); __builtin_amdgcn_s_barrier();
    stage((kt + 4) * 64, 1 * 2048, 1 * 4096); comp(smA + 4096, smB + 8192);
    asm volatile("s_waitcnt vmcnt(3)" ::: "memory"); __builtin_amdgcn_s_barrier();
  }
  comp(smA, smB);                              // tile NT-2 (buf0: 126%3==0)
  asm volatile("s_waitcnt vmcnt(0)" ::: "memory");
  __builtin_amdgcn_s_barrier();
  comp(smA + 2048, smB + 4096);                // tile NT-1 (buf1)

  // D^T: value(i,j,r) at token-slot c = mb*64+wm+i*16+fr, n = wn+j*16+fq*4+r
  const int nE = ne[e];
  float4 b2v[4];
  #pragma unroll
  for (int j = 0; j < 4; ++j)
    b2v[j] = *(const float4*)&b2[e * ODIM + nb * 128 + wn + j * 16 + fq * 4];
  #pragma unroll
  for (int i = 0; i < 2; ++i) {
    int c = mb * 64 + wm + i * 16 + fr;
    if (c < nE) {
      int s = perm[e * CAP + c];
      float g = gval[s];
      float* orow = out + (size_t)s * ODIM + nb * 128 + wn + fq * 4;
      #pragma unroll
      for (int j = 0; j < 4; ++j) {
        float4 o;
        o.x = (acc[i][j][0] + b2v[j].x) * g;
        o.y = (acc[i][j][1] + b2v[j].y) * g;
        o.z = (acc[i][j][2] + b2v[j].z) * g;
        o.w = (acc[i][j][3] + b2v[j].w) * g;
        *(float4*)&orow[j * 16] = o;
      }
    }
  }
}

// ------------------------------- launch ---------------------------------------
extern "C" void kernel_launch(void* const* d_in, const int* in_sizes, int n_in,
                              void* d_out, int out_size, void* d_ws, size_t ws_size,
                              hipStream_t stream) {
  const float* feat = (const float*)d_in[0];
  const float* gw   = (const float*)d_in[1];
  const float* w1   = (const float*)d_in[2];
  const float* b1   = (const float*)d_in[3];
  const float* w2   = (const float*)d_in[4];
  const float* b2   = (const float*)d_in[5];
  float* out = (float*)d_out;

  char* ws = (char*)d_ws;
  unsigned short* wt   = (unsigned short*)(ws);                  // 33,554,432 B
  unsigned short* hbuf = (unsigned short*)(ws + 33554432);       // 67,108,864 B
  unsigned short* disp = (unsigned short*)(ws + 100663296);      // 16,777,216 B
  int*   idx  = (int*)  (ws + 117440512);
  float* gval = (float*)(ws + 117473280);
  int*   perm = (int*)  (ws + 117506048);
  float* gsum = (float*)(ws + 117538816);
  int*   ne   = (int*)  (ws + 117538832);

  hipMemsetAsync(ws + 117538816, 0, 32, stream);

  // prep = gate (2048) + w1 transpose (4096) + d_out zero (2048)
  prep_kernel<<<2048 + 4096 + 2048, 256, 0, stream>>>(
      feat, gw, w1, idx, gval, gsum, wt, out);
  scan_kernel<<<1, 1024, 0, stream>>>(idx, perm, ne, gsum, out + (size_t)S_TOK * ODIM);
  gather_kernel<<<NEXP * CAP, 256, 0, stream>>>(feat, perm, ne, disp);
  fc1_kernel<<<dim3(HDIM / 128, CAP / 128, NEXP), 256, 0, stream>>>(disp, wt, b1, hbuf);
  transpose_cast<<<dim3(ODIM / 64, HDIM / 64, NEXP), 256, 0, stream>>>(w2, wt, HDIM, ODIM);
  fc2_kernel<<<1024, 256, 0, stream>>>(hbuf, wt, b2, perm, ne, gval, out);
}